// Round 8
// baseline (187.576 us; speedup 1.0000x reference)
//
#include <hip/hip_runtime.h>
#include <hip/hip_bf16.h>
#include <stdint.h>

#define NN 4096
#define BATCH 1024
#define SEG 64          // carry granularity (steps)
#define NSEG 64
#define DPAD 8192
#define DGRP 128        // diagonals per pass3 block (sign-pure since NN-1 = 4095 ≡ 127 mod 128)
#define TSEG 64         // steps per pass3 block (== SEG)

#define WS_PART_OFF 44171264u
#define WS_SK2_NEED (WS_PART_OFF + (size_t)BATCH * NN * 4)
#define WS_SK4_NEED (WS_PART_OFF + 3ull * BATCH * NN * 4)

typedef __bf16 bf16x8 __attribute__((ext_vector_type(8)));
typedef float f32x4 __attribute__((ext_vector_type(4)));

__device__ __forceinline__ unsigned short f2bf(float f) {
    uint32_t u = __builtin_bit_cast(uint32_t, f);
    uint32_t r = (u + 0x7FFFu + ((u >> 16) & 1u)) >> 16;
    return (unsigned short)r;
}

// ---- transpose G,H (R x N, R=4) into float4-per-position arrays ----
__global__ void k_prep(const float* __restrict__ G, const float* __restrict__ H,
                       float4* __restrict__ G4, float4* __restrict__ H4) {
    int p = blockIdx.x * 256 + threadIdx.x;
    if (p < NN) {
        G4[p] = make_float4(G[p], G[NN + p], G[2 * NN + p], G[3 * NN + p]);
        H4[p] = make_float4(H[p], H[NN + p], H[2 * NN + p], H[3 * NN + p]);
    }
}

// ---- convert x fp32 -> bf16 ----
__global__ void k_convert(const float4* __restrict__ x4, ushort4* __restrict__ xb4) {
    int t = blockIdx.x * 256 + threadIdx.x;
    float4 a = x4[t];
    ushort4 o;
    o.x = f2bf(a.x); o.y = f2bf(a.y); o.z = f2bf(a.z); o.w = f2bf(a.w);
    xb4[t] = o;
}

// ---- pass 1: per-(diagonal, 64-step segment) affine map ----
__global__ void k_pass1(const float4* __restrict__ G4, const float4* __restrict__ H4,
                        const float* __restrict__ sA, const float* __restrict__ sB,
                        float2* __restrict__ seg) {
    int tid = blockIdx.x * 256 + threadIdx.x;
    int s = tid >> 13;
    int dd = tid & (DPAD - 1);
    int o = dd - (NN - 1);
    if (o > NN - 1) return;
    int ao = o < 0 ? -o : o;
    int L = NN - ao;
    int nseg = (L + SEG - 1) >> 6;
    if (s >= nseg) return;
    int t0 = s * SEG;
    int tend = t0 + SEG; if (tend > L) tend = L;
    float M = 0.f, Aacc = 1.f;
    for (int t = t0; t < tend; ++t) {
        int i = (o >= 0) ? (t + o) : t;
        int k = (o >= 0) ? t : (t - o);
        float4 g = G4[i], h = H4[k];
        float f = g.x * h.x + g.y * h.y + g.z * h.z + g.w * h.w;
        float c = (t == 0) ? 0.f : sA[i - 1] * sB[k - 1];
        M = fmaf(c, M, f);
        Aacc *= c;
    }
    seg[(size_t)s * DPAD + dd] = make_float2(Aacc, M);
}

// ---- pass 2: scan affine maps along each diagonal -> carry-in per segment ----
__global__ void k_pass2(const float2* __restrict__ seg, float* __restrict__ carr) {
    int dd = blockIdx.x * 256 + threadIdx.x;
    if (dd >= DPAD) return;
    int o = dd - (NN - 1);
    if (o > NN - 1) return;
    int ao = o < 0 ? -o : o;
    int L = NN - ao;
    int nseg = (L + SEG - 1) >> 6;
    float Min = 0.f;
    for (int s = 0; s < nseg; ++s) {
        carr[(size_t)s * DPAD + dd] = Min;
        float2 ab = seg[(size_t)s * DPAD + dd];
        Min = fmaf(ab.x, Min, ab.y);
    }
}

// ---- pass 3: sign-pure parallelogram tiles, 24.4 KB LDS (6 blocks/CU), 128 thr.
__global__ __launch_bounds__(128) void k_pass3t(
        const float4* __restrict__ G4, const float4* __restrict__ H4,
        const float* __restrict__ sA, const float* __restrict__ sB,
        const float* __restrict__ carr, unsigned short* __restrict__ V) {
    __shared__ unsigned short vals[191 * 64];   // 24,448 B (NEG uses first 16 KB)

    int dg = blockIdx.x;   // 0..63
    int sg = blockIdx.y;   // 0..63
    int dd0 = dg * DGRP;
    int t0 = sg * TSEG;
    int o0 = dd0 - (NN - 1);
    int o_hi = o0 + DGRP - 1;

    int minabs = (o0 >= 0) ? o0 : ((o_hi < 0) ? -o_hi : 0);
    if (t0 >= NN - minabs) return;

    int tid = threadIdx.x;   // 0..127, one diagonal each
    int dd = dd0 + tid;
    int o = dd - (NN - 1);
    float M = carr[(size_t)sg * DPAD + dd];

    if (o_hi <= 0) {
        // ---- NEG: i = t0+tl (uniform), k = t0+tl-o (per-lane, coalesced) ----
        int k0 = t0 - o;
#pragma unroll 4
        for (int tl = 0; tl < TSEG; ++tl) {
            int i = t0 + tl;
            int k = k0 + tl;
            int kc = k < NN ? k : NN - 1;
            float4 g = G4[i], h = H4[kc];
            float f = g.x * h.x + g.y * h.y + g.z * h.z + g.w * h.w;
            float c = 0.f;
            if (t0 + tl != 0) c = sA[i - 1] * sB[kc - 1];
            M = fmaf(c, M, f);
            vals[tl * 128 + ((k & 127) ^ ((tl & 15) << 2))] = f2bf(M);
        }
        __syncthreads();

        int row_sub = tid >> 5, csub = tid & 31;
        for (int rb = 0; rb < TSEG; rb += 4) {
            int tl = rb + row_sub;
            int i = t0 + tl;
            int swz = (tl & 15) << 2;
            int k_lo = i - o_hi;
            int k_hi = i - o0; if (k_hi > NN - 1) k_hi = NN - 1;
            size_t rowbase = (size_t)i * NN;
            int cb_first = k_lo >> 2, cb_last = k_hi >> 2;
            for (int cc = cb_first + csub; cc <= cb_last; cc += 32) {
                int kb = cc << 2;
                if (kb >= k_lo && kb + 3 <= k_hi) {
                    int c0 = (kb & 127) ^ swz;
                    *(ushort4*)&V[rowbase + kb] = *(const ushort4*)&vals[tl * 128 + c0];
                } else {
#pragma unroll
                    for (int j = 0; j < 4; ++j) {
                        int k = kb + j;
                        if (k < k_lo || k > k_hi) continue;
                        V[rowbase + k] = vals[tl * 128 + ((k & 127) ^ swz)];
                    }
                }
            }
        }
    } else {
        // ---- POS: k = t0+tl (uniform), i = t0+tl+o (per-lane, coalesced) ----
        int i0p = t0 + o;
#pragma unroll 4
        for (int tl = 0; tl < TSEG; ++tl) {
            int i = i0p + tl;
            int k = t0 + tl;
            int ic = i < NN ? i : NN - 1;
            float4 g = G4[ic], h = H4[k];
            float f = g.x * h.x + g.y * h.y + g.z * h.z + g.w * h.w;
            float c = 0.f;
            if (t0 + tl != 0) c = sA[ic - 1] * sB[k - 1];
            M = fmaf(c, M, f);
            int rr = tl + tid;
            vals[rr * 64 + ((k & 63) ^ ((rr & 15) << 2))] = f2bf(M);
        }
        __syncthreads();

        int i_lo = t0 + o0;
        int i_hi = t0 + TSEG - 1 + o_hi; if (i_hi > NN - 1) i_hi = NN - 1;
        int nrows = i_hi - i_lo + 1;
        int row_sub = tid >> 4, csub = tid & 15;
        for (int rb = 0; rb < nrows; rb += 8) {
            int rr = rb + row_sub;
            int i = i_lo + rr;
            if (i > i_hi) continue;
            int swz = (rr & 15) << 2;
            int k_lo = i - o_hi; if (k_lo < t0) k_lo = t0;
            int k_hi = i - o0;  if (k_hi > t0 + TSEG - 1) k_hi = t0 + TSEG - 1;
            size_t rowbase = (size_t)i * NN;
            int cb_first = k_lo >> 2, cb_last = k_hi >> 2;
            for (int cc = cb_first + csub; cc <= cb_last; cc += 16) {
                int kb = cc << 2;
                if (kb >= k_lo && kb + 3 <= k_hi) {
                    int c0 = (kb & 63) ^ swz;
                    *(ushort4*)&V[rowbase + kb] = *(const ushort4*)&vals[rr * 64 + c0];
                } else {
#pragma unroll
                    for (int j = 0; j < 4; ++j) {
                        int k = kb + j;
                        if (k < k_lo || k > k_hi) continue;
                        V[rowbase + k] = vals[rr * 64 + ((k & 63) ^ swz)];
                    }
                }
            }
        }
    }
}

// ---- split-K=4 GEMM, m97-exact single-buffer. 128x128 tile, BK=64, 4 waves of
// 64x64, 32 KB LDS, grid (8,32,4)=1024 blocks = 4/CU. z=0 -> C, z>=1 -> part.
__global__ __launch_bounds__(256, 4) void k_gemm_sk4(const unsigned short* __restrict__ A,
                                                     const unsigned short* __restrict__ Bv,
                                                     float* __restrict__ C,
                                                     float* __restrict__ part) {
    __shared__ unsigned short lA[128 * 64];   // 16 KB
    __shared__ unsigned short lB[128 * 64];   // 16 KB

    // bijective XCD swizzle over 1024 blocks; one XCD covers 4 bn-panels (4 MB V = L2)
    int flat = (blockIdx.z * 32 + blockIdx.y) * 8 + blockIdx.x;
    int swz = (flat & 7) * 128 + (flat >> 3);
    int bz = swz & 3;
    int bm = (swz >> 2) & 7;
    int bn = swz >> 5;

    int tid = threadIdx.x;
    int lane = tid & 63;
    int wid = tid >> 6;
    int wm = wid >> 1, wn = wid & 1;

    int kbase = bz * (NN / 4);

    const unsigned short* aptr[4];
    const unsigned short* bptr[4];
#pragma unroll
    for (int c = 0; c < 4; ++c) {
        int u = c * 256 + tid;
        aptr[c] = A + ((size_t)(bm * 128 + (u >> 3)) * NN) + kbase + (u & 7) * 8;
        bptr[c] = Bv + ((size_t)(bn * 128 + (u >> 3)) * NN) + kbase + (u & 7) * 8;
    }

    f32x4 acc[4][4];
#pragma unroll
    for (int i = 0; i < 4; ++i)
#pragma unroll
        for (int j = 0; j < 4; ++j) acc[i][j] = (f32x4){0.f, 0.f, 0.f, 0.f};

    for (int kt = 0; kt < NN / 4 / 64; ++kt) {
#pragma unroll
        for (int c = 0; c < 4; ++c) {
            __builtin_amdgcn_global_load_lds(
                (const __attribute__((address_space(1))) uint32_t*)(aptr[c]),
                (__attribute__((address_space(3))) uint32_t*)(&lA[(c * 256 + tid) * 8]), 16, 0, 0);
            aptr[c] += 64;
            __builtin_amdgcn_global_load_lds(
                (const __attribute__((address_space(1))) uint32_t*)(bptr[c]),
                (__attribute__((address_space(3))) uint32_t*)(&lB[(c * 256 + tid) * 8]), 16, 0, 0);
            bptr[c] += 64;
        }
        __syncthreads();   // drains vmcnt -> LDS ready
#pragma unroll
        for (int kk = 0; kk < 2; ++kk) {
            bf16x8 af[4], bfr[4];
#pragma unroll
            for (int mf = 0; mf < 4; ++mf)
                af[mf] = *(const bf16x8*)&lA[(wm * 64 + mf * 16 + (lane & 15)) * 64 + kk * 32 + (lane >> 4) * 8];
#pragma unroll
            for (int nf = 0; nf < 4; ++nf)
                bfr[nf] = *(const bf16x8*)&lB[(wn * 64 + nf * 16 + (lane & 15)) * 64 + kk * 32 + (lane >> 4) * 8];
#pragma unroll
            for (int mf = 0; mf < 4; ++mf)
#pragma unroll
                for (int nf = 0; nf < 4; ++nf)
                    acc[mf][nf] = __builtin_amdgcn_mfma_f32_16x16x32_bf16(af[mf], bfr[nf], acc[mf][nf], 0, 0, 0);
        }
        __syncthreads();   // all waves done reading before next stage overwrites
    }

    float* dst = (bz == 0) ? C : (part + (size_t)(bz - 1) * BATCH * NN);
#pragma unroll
    for (int nf = 0; nf < 4; ++nf) {
        int col = bn * 128 + wn * 64 + nf * 16 + (lane & 15);
#pragma unroll
        for (int mf = 0; mf < 4; ++mf) {
            f32x4 v = acc[mf][nf];
            int row0 = bm * 128 + wm * 64 + mf * 16 + (lane >> 4) * 4;
#pragma unroll
            for (int r = 0; r < 4; ++r)
                dst[(size_t)(row0 + r) * NN + col] = v[r];
        }
    }
}

// ---- reduce4: C += part0+part1+part2 + bias ----
__global__ void k_reduce4(float4* __restrict__ C, const float4* __restrict__ p0,
                          const float4* __restrict__ p1, const float4* __restrict__ p2,
                          const float4* __restrict__ bias4) {
    int idx = blockIdx.x * 256 + threadIdx.x;   // BATCH*NN/4 exactly
    float4 c = C[idx], a = p0[idx], b = p1[idx], d = p2[idx];
    float4 e = bias4[idx & (NN / 4 - 1)];
    C[idx] = make_float4(c.x + a.x + b.x + d.x + e.x,
                         c.y + a.y + b.y + d.y + e.y,
                         c.z + a.z + b.z + d.z + e.z,
                         c.w + a.w + b.w + d.w + e.w);
}

// ---- split-K=2 GEMM (R7 path, used if ws too small for sk4) ----
__global__ __launch_bounds__(256) void k_gemm_sk(const unsigned short* __restrict__ A,
                                                 const unsigned short* __restrict__ Bv,
                                                 float* __restrict__ C,
                                                 float* __restrict__ part) {
    __shared__ unsigned short lA[2][128 * 64];
    __shared__ unsigned short lB[2][128 * 64];

    int flat = (blockIdx.z * 32 + blockIdx.y) * 8 + blockIdx.x;
    int swz = (flat & 7) * 64 + (flat >> 3);
    int bz = swz & 1;
    int bm = (swz >> 1) & 7;
    int bn = swz >> 4;

    int tid = threadIdx.x;
    int lane = tid & 63;
    int wid = tid >> 6;
    int wm = wid >> 1, wn = wid & 1;

    int kbase = bz * (NN / 2);

    const unsigned short* aptr[4];
    const unsigned short* bptr[4];
#pragma unroll
    for (int c = 0; c < 4; ++c) {
        int u = c * 256 + tid;
        aptr[c] = A + ((size_t)(bm * 128 + (u >> 3)) * NN) + kbase + (u & 7) * 8;
        bptr[c] = Bv + ((size_t)(bn * 128 + (u >> 3)) * NN) + kbase + (u & 7) * 8;
    }

    f32x4 acc[4][4];
#pragma unroll
    for (int i = 0; i < 4; ++i)
#pragma unroll
        for (int j = 0; j < 4; ++j) acc[i][j] = (f32x4){0.f, 0.f, 0.f, 0.f};

#define STAGE_SK(buf)                                                                \
    do {                                                                             \
        _Pragma("unroll") for (int c = 0; c < 4; ++c) {                              \
            __builtin_amdgcn_global_load_lds(                                        \
                (const __attribute__((address_space(1))) uint32_t*)(aptr[c]),        \
                (__attribute__((address_space(3))) uint32_t*)(&lA[buf][(c * 256 + tid) * 8]), \
                16, 0, 0);                                                           \
            aptr[c] += 64;                                                           \
            __builtin_amdgcn_global_load_lds(                                        \
                (const __attribute__((address_space(1))) uint32_t*)(bptr[c]),        \
                (__attribute__((address_space(3))) uint32_t*)(&lB[buf][(c * 256 + tid) * 8]), \
                16, 0, 0);                                                           \
            bptr[c] += 64;                                                           \
        }                                                                            \
    } while (0)

#define COMPUTE_SK(buf)                                                              \
    do {                                                                             \
        _Pragma("unroll") for (int kk = 0; kk < 2; ++kk) {                           \
            bf16x8 af[4], bfr[4];                                                    \
            _Pragma("unroll") for (int mf = 0; mf < 4; ++mf)                         \
                af[mf] = *(const bf16x8*)&lA[buf][(wm * 64 + mf * 16 + (lane & 15)) * 64 + kk * 32 + (lane >> 4) * 8]; \
            _Pragma("unroll") for (int nf = 0; nf < 4; ++nf)                         \
                bfr[nf] = *(const bf16x8*)&lB[buf][(wn * 64 + nf * 16 + (lane & 15)) * 64 + kk * 32 + (lane >> 4) * 8]; \
            _Pragma("unroll") for (int mf = 0; mf < 4; ++mf)                         \
                _Pragma("unroll") for (int nf = 0; nf < 4; ++nf)                     \
                    acc[mf][nf] = __builtin_amdgcn_mfma_f32_16x16x32_bf16(af[mf], bfr[nf], acc[mf][nf], 0, 0, 0); \
        }                                                                            \
    } while (0)

    STAGE_SK(0);
    __syncthreads();
    int cur = 0;
    for (int kt = 0; kt < NN / 2 / 64 - 1; ++kt) {
        STAGE_SK(cur ^ 1);
        COMPUTE_SK(cur);
        __syncthreads();
        cur ^= 1;
    }
    COMPUTE_SK(cur);
#undef STAGE_SK
#undef COMPUTE_SK

    float* dst = bz ? part : C;
#pragma unroll
    for (int nf = 0; nf < 4; ++nf) {
        int col = bn * 128 + wn * 64 + nf * 16 + (lane & 15);
#pragma unroll
        for (int mf = 0; mf < 4; ++mf) {
            f32x4 v = acc[mf][nf];
            int row0 = bm * 128 + wm * 64 + mf * 16 + (lane >> 4) * 4;
#pragma unroll
            for (int r = 0; r < 4; ++r)
                dst[(size_t)(row0 + r) * NN + col] = v[r];
        }
    }
}

// ---- reduce (split-K=2): out = C + part + bias ----
__global__ void k_reduce(float4* __restrict__ C, const float4* __restrict__ part,
                         const float4* __restrict__ bias4) {
    int idx = blockIdx.x * 256 + threadIdx.x;
    float4 p = C[idx];
    float4 q = part[idx];
    float4 b = bias4[idx & (NN / 4 - 1)];
    C[idx] = make_float4(p.x + q.x + b.x, p.y + q.y + b.y,
                         p.z + q.z + b.z, p.w + q.w + b.w);
}

// ---- fallback GEMM (no split): BM=64 x BN=128 ----
__global__ __launch_bounds__(256) void k_gemm(const unsigned short* __restrict__ A,
                                              const unsigned short* __restrict__ Bv,
                                              const float* __restrict__ bias,
                                              float* __restrict__ C) {
    __shared__ unsigned short lA[2][64 * 64];
    __shared__ unsigned short lB[2][128 * 64];

    int flat = blockIdx.y * 16 + blockIdx.x;
    int wg = (flat & 7) * 64 + (flat >> 3);
    int bm = wg & 15;
    int bn = wg >> 4;

    int tid = threadIdx.x;
    int lane = tid & 63;
    int wid = tid >> 6;
    int wm = wid >> 1, wn = wid & 1;

    const unsigned short* aptr[2];
    const unsigned short* bptr[4];
#pragma unroll
    for (int c = 0; c < 2; ++c) {
        int u = c * 256 + tid;
        aptr[c] = A + ((size_t)(bm * 64 + (u >> 3)) * NN) + (u & 7) * 8;
    }
#pragma unroll
    for (int c = 0; c < 4; ++c) {
        int u = c * 256 + tid;
        bptr[c] = Bv + ((size_t)(bn * 128 + (u >> 3)) * NN) + (u & 7) * 8;
    }

    f32x4 acc[2][4];
#pragma unroll
    for (int i = 0; i < 2; ++i)
#pragma unroll
        for (int j = 0; j < 4; ++j) acc[i][j] = (f32x4){0.f, 0.f, 0.f, 0.f};

#define STAGE(buf)                                                                   \
    do {                                                                             \
        _Pragma("unroll") for (int c = 0; c < 2; ++c) {                              \
            __builtin_amdgcn_global_load_lds(                                        \
                (const __attribute__((address_space(1))) uint32_t*)(aptr[c]),        \
                (__attribute__((address_space(3))) uint32_t*)(&lA[buf][(c * 256 + tid) * 8]), \
                16, 0, 0);                                                           \
            aptr[c] += 64;                                                           \
        }                                                                            \
        _Pragma("unroll") for (int c = 0; c < 4; ++c) {                              \
            __builtin_amdgcn_global_load_lds(                                        \
                (const __attribute__((address_space(1))) uint32_t*)(bptr[c]),        \
                (__attribute__((address_space(3))) uint32_t*)(&lB[buf][(c * 256 + tid) * 8]), \
                16, 0, 0);                                                           \
            bptr[c] += 64;                                                           \
        }                                                                            \
    } while (0)

#define COMPUTE(buf)                                                                 \
    do {                                                                             \
        _Pragma("unroll") for (int kk = 0; kk < 2; ++kk) {                           \
            bf16x8 af[2], bfr[4];                                                    \
            _Pragma("unroll") for (int mf = 0; mf < 2; ++mf)                         \
                af[mf] = *(const bf16x8*)&lA[buf][(wm * 32 + mf * 16 + (lane & 15)) * 64 + kk * 32 + (lane >> 4) * 8]; \
            _Pragma("unroll") for (int nf = 0; nf < 4; ++nf)                         \
                bfr[nf] = *(const bf16x8*)&lB[buf][(wn * 64 + nf * 16 + (lane & 15)) * 64 + kk * 32 + (lane >> 4) * 8]; \
            _Pragma("unroll") for (int mf = 0; mf < 2; ++mf)                         \
                _Pragma("unroll") for (int nf = 0; nf < 4; ++nf)                     \
                    acc[mf][nf] = __builtin_amdgcn_mfma_f32_16x16x32_bf16(af[mf], bfr[nf], acc[mf][nf], 0, 0, 0); \
        }                                                                            \
    } while (0)

    STAGE(0);
    __syncthreads();
    int cur = 0;
    for (int kt = 0; kt < NN / 64 - 1; ++kt) {
        STAGE(cur ^ 1);
        COMPUTE(cur);
        __syncthreads();
        cur ^= 1;
    }
    COMPUTE(cur);
#undef STAGE
#undef COMPUTE

#pragma unroll
    for (int nf = 0; nf < 4; ++nf) {
        int col = bn * 128 + wn * 64 + nf * 16 + (lane & 15);
        float bv = bias[col];
#pragma unroll
        for (int mf = 0; mf < 2; ++mf) {
            f32x4 v = acc[mf][nf];
            int row0 = bm * 64 + wm * 32 + mf * 16 + (lane >> 4) * 4;
#pragma unroll
            for (int r = 0; r < 4; ++r)
                C[(size_t)(row0 + r) * NN + col] = v[r] + bv;
        }
    }
}

extern "C" void kernel_launch(void* const* d_in, const int* in_sizes, int n_in,
                              void* d_out, int out_size, void* d_ws, size_t ws_size,
                              hipStream_t stream) {
    (void)in_sizes; (void)n_in; (void)out_size;
    const float* x  = (const float*)d_in[0];
    const float* sA = (const float*)d_in[1];
    const float* sB = (const float*)d_in[2];
    const float* G  = (const float*)d_in[3];
    const float* H  = (const float*)d_in[4];
    const float* bias = (const float*)d_in[5];
    float* out = (float*)d_out;

    char* ws = (char*)d_ws;
    unsigned short* V  = (unsigned short*)ws;               // 33,554,432 B
    float2* seg = (float2*)ws;                              // 4 MB, aliased on V (dead before pass3)
    unsigned short* xb = (unsigned short*)(ws + 33554432);  // 8,388,608 B
    float4* G4 = (float4*)(ws + 41943040);                  // 65,536 B
    float4* H4 = (float4*)(ws + 42008576);                  // 65,536 B
    float* carr = (float*)(ws + 42074112);                  // 2,097,152 B
    float* part = (float*)(ws + WS_PART_OFF);               // up to 3 x 16,777,216 B

    hipLaunchKernelGGL(k_prep, dim3(16), dim3(256), 0, stream, G, H, G4, H4);
    hipLaunchKernelGGL(k_convert, dim3((BATCH * NN / 4) / 256), dim3(256), 0, stream,
                       (const float4*)x, (ushort4*)xb);
    hipLaunchKernelGGL(k_pass1, dim3((NSEG * DPAD) / 256), dim3(256), 0, stream,
                       G4, H4, sA, sB, seg);
    hipLaunchKernelGGL(k_pass2, dim3(DPAD / 256), dim3(256), 0, stream, seg, carr);
    hipLaunchKernelGGL(k_pass3t, dim3(DPAD / DGRP, NN / TSEG), dim3(128), 0, stream,
                       G4, H4, sA, sB, carr, V);

    if (ws_size >= WS_SK4_NEED) {
        hipLaunchKernelGGL(k_gemm_sk4, dim3(8, 32, 4), dim3(256), 0, stream,
                           xb, V, out, part);
        hipLaunchKernelGGL(k_reduce4, dim3((BATCH * NN / 4) / 256), dim3(256), 0, stream,
                           (float4*)out, (const float4*)part,
                           (const float4*)(part + (size_t)BATCH * NN),
                           (const float4*)(part + 2ull * BATCH * NN),
                           (const float4*)bias);
    } else if (ws_size >= WS_SK2_NEED) {
        hipLaunchKernelGGL(k_gemm_sk, dim3(8, 32, 2), dim3(256), 0, stream,
                           xb, V, out, part);
        hipLaunchKernelGGL(k_reduce, dim3((BATCH * NN / 4) / 256), dim3(256), 0, stream,
                           (float4*)out, (const float4*)part, (const float4*)bias);
    } else {
        hipLaunchKernelGGL(k_gemm, dim3(BATCH / 64, NN / 128), dim3(256), 0, stream,
                           xb, V, bias, out);
    }
}

// Round 9
// 182.797 us; speedup vs baseline: 1.0261x; 1.0261x over previous
//
#include <hip/hip_runtime.h>
#include <hip/hip_bf16.h>
#include <stdint.h>

#define NN 4096
#define BATCH 1024
#define SEG 64          // carry granularity (steps)
#define NSEG 64
#define DPAD 8192
#define DGRP 128        // diagonals per pass3 block (sign-pure since NN-1 = 4095 ≡ 127 mod 128)
#define TSEG 64         // steps per pass3 block (== SEG)

#define WS_PART_OFF 44171264u
#define WS_SK2_NEED (WS_PART_OFF + (size_t)BATCH * NN * 4)
#define WS_SK4_NEED (WS_PART_OFF + 3ull * BATCH * NN * 4)

typedef __bf16 bf16x8 __attribute__((ext_vector_type(8)));
typedef float f32x4 __attribute__((ext_vector_type(4)));

__device__ __forceinline__ unsigned short f2bf(float f) {
    uint32_t u = __builtin_bit_cast(uint32_t, f);
    uint32_t r = (u + 0x7FFFu + ((u >> 16) & 1u)) >> 16;
    return (unsigned short)r;
}

// ---- transpose G,H (R x N, R=4) into float4-per-position arrays ----
__global__ void k_prep(const float* __restrict__ G, const float* __restrict__ H,
                       float4* __restrict__ G4, float4* __restrict__ H4) {
    int p = blockIdx.x * 256 + threadIdx.x;
    if (p < NN) {
        G4[p] = make_float4(G[p], G[NN + p], G[2 * NN + p], G[3 * NN + p]);
        H4[p] = make_float4(H[p], H[NN + p], H[2 * NN + p], H[3 * NN + p]);
    }
}

// ---- convert x fp32 -> bf16 ----
__global__ void k_convert(const float4* __restrict__ x4, ushort4* __restrict__ xb4) {
    int t = blockIdx.x * 256 + threadIdx.x;
    float4 a = x4[t];
    ushort4 o;
    o.x = f2bf(a.x); o.y = f2bf(a.y); o.z = f2bf(a.z); o.w = f2bf(a.w);
    xb4[t] = o;
}

// ---- pass 1: per-(diagonal, 64-step segment) affine map ----
__global__ void k_pass1(const float4* __restrict__ G4, const float4* __restrict__ H4,
                        const float* __restrict__ sA, const float* __restrict__ sB,
                        float2* __restrict__ seg) {
    int tid = blockIdx.x * 256 + threadIdx.x;
    int s = tid >> 13;
    int dd = tid & (DPAD - 1);
    int o = dd - (NN - 1);
    if (o > NN - 1) return;
    int ao = o < 0 ? -o : o;
    int L = NN - ao;
    int nseg = (L + SEG - 1) >> 6;
    if (s >= nseg) return;
    int t0 = s * SEG;
    int tend = t0 + SEG; if (tend > L) tend = L;
    float M = 0.f, Aacc = 1.f;
    for (int t = t0; t < tend; ++t) {
        int i = (o >= 0) ? (t + o) : t;
        int k = (o >= 0) ? t : (t - o);
        float4 g = G4[i], h = H4[k];
        float f = g.x * h.x + g.y * h.y + g.z * h.z + g.w * h.w;
        float c = (t == 0) ? 0.f : sA[i - 1] * sB[k - 1];
        M = fmaf(c, M, f);
        Aacc *= c;
    }
    seg[(size_t)s * DPAD + dd] = make_float2(Aacc, M);
}

// ---- pass 2: scan affine maps along each diagonal -> carry-in per segment ----
__global__ void k_pass2(const float2* __restrict__ seg, float* __restrict__ carr) {
    int dd = blockIdx.x * 256 + threadIdx.x;
    if (dd >= DPAD) return;
    int o = dd - (NN - 1);
    if (o > NN - 1) return;
    int ao = o < 0 ? -o : o;
    int L = NN - ao;
    int nseg = (L + SEG - 1) >> 6;
    float Min = 0.f;
    for (int s = 0; s < nseg; ++s) {
        carr[(size_t)s * DPAD + dd] = Min;
        float2 ab = seg[(size_t)s * DPAD + dd];
        Min = fmaf(ab.x, Min, ab.y);
    }
}

// ---- pass 3: sign-pure parallelogram tiles, 24.4 KB LDS (6 blocks/CU), 128 thr.
__global__ __launch_bounds__(128) void k_pass3t(
        const float4* __restrict__ G4, const float4* __restrict__ H4,
        const float* __restrict__ sA, const float* __restrict__ sB,
        const float* __restrict__ carr, unsigned short* __restrict__ V) {
    __shared__ unsigned short vals[191 * 64];   // 24,448 B (NEG uses first 16 KB)

    int dg = blockIdx.x;   // 0..63
    int sg = blockIdx.y;   // 0..63
    int dd0 = dg * DGRP;
    int t0 = sg * TSEG;
    int o0 = dd0 - (NN - 1);
    int o_hi = o0 + DGRP - 1;

    int minabs = (o0 >= 0) ? o0 : ((o_hi < 0) ? -o_hi : 0);
    if (t0 >= NN - minabs) return;

    int tid = threadIdx.x;   // 0..127, one diagonal each
    int dd = dd0 + tid;
    int o = dd - (NN - 1);
    float M = carr[(size_t)sg * DPAD + dd];

    if (o_hi <= 0) {
        // ---- NEG: i = t0+tl (uniform), k = t0+tl-o (per-lane, coalesced) ----
        int k0 = t0 - o;
#pragma unroll 4
        for (int tl = 0; tl < TSEG; ++tl) {
            int i = t0 + tl;
            int k = k0 + tl;
            int kc = k < NN ? k : NN - 1;
            float4 g = G4[i], h = H4[kc];
            float f = g.x * h.x + g.y * h.y + g.z * h.z + g.w * h.w;
            float c = 0.f;
            if (t0 + tl != 0) c = sA[i - 1] * sB[kc - 1];
            M = fmaf(c, M, f);
            vals[tl * 128 + ((k & 127) ^ ((tl & 15) << 2))] = f2bf(M);
        }
        __syncthreads();

        int row_sub = tid >> 5, csub = tid & 31;
        for (int rb = 0; rb < TSEG; rb += 4) {
            int tl = rb + row_sub;
            int i = t0 + tl;
            int swz = (tl & 15) << 2;
            int k_lo = i - o_hi;
            int k_hi = i - o0; if (k_hi > NN - 1) k_hi = NN - 1;
            size_t rowbase = (size_t)i * NN;
            int cb_first = k_lo >> 2, cb_last = k_hi >> 2;
            for (int cc = cb_first + csub; cc <= cb_last; cc += 32) {
                int kb = cc << 2;
                if (kb >= k_lo && kb + 3 <= k_hi) {
                    int c0 = (kb & 127) ^ swz;
                    *(ushort4*)&V[rowbase + kb] = *(const ushort4*)&vals[tl * 128 + c0];
                } else {
#pragma unroll
                    for (int j = 0; j < 4; ++j) {
                        int k = kb + j;
                        if (k < k_lo || k > k_hi) continue;
                        V[rowbase + k] = vals[tl * 128 + ((k & 127) ^ swz)];
                    }
                }
            }
        }
    } else {
        // ---- POS: k = t0+tl (uniform), i = t0+tl+o (per-lane, coalesced) ----
        int i0p = t0 + o;
#pragma unroll 4
        for (int tl = 0; tl < TSEG; ++tl) {
            int i = i0p + tl;
            int k = t0 + tl;
            int ic = i < NN ? i : NN - 1;
            float4 g = G4[ic], h = H4[k];
            float f = g.x * h.x + g.y * h.y + g.z * h.z + g.w * h.w;
            float c = 0.f;
            if (t0 + tl != 0) c = sA[ic - 1] * sB[k - 1];
            M = fmaf(c, M, f);
            int rr = tl + tid;
            vals[rr * 64 + ((k & 63) ^ ((rr & 15) << 2))] = f2bf(M);
        }
        __syncthreads();

        int i_lo = t0 + o0;
        int i_hi = t0 + TSEG - 1 + o_hi; if (i_hi > NN - 1) i_hi = NN - 1;
        int nrows = i_hi - i_lo + 1;
        int row_sub = tid >> 4, csub = tid & 15;
        for (int rb = 0; rb < nrows; rb += 8) {
            int rr = rb + row_sub;
            int i = i_lo + rr;
            if (i > i_hi) continue;
            int swz = (rr & 15) << 2;
            int k_lo = i - o_hi; if (k_lo < t0) k_lo = t0;
            int k_hi = i - o0;  if (k_hi > t0 + TSEG - 1) k_hi = t0 + TSEG - 1;
            size_t rowbase = (size_t)i * NN;
            int cb_first = k_lo >> 2, cb_last = k_hi >> 2;
            for (int cc = cb_first + csub; cc <= cb_last; cc += 16) {
                int kb = cc << 2;
                if (kb >= k_lo && kb + 3 <= k_hi) {
                    int c0 = (kb & 63) ^ swz;
                    *(ushort4*)&V[rowbase + kb] = *(const ushort4*)&vals[rr * 64 + c0];
                } else {
#pragma unroll
                    for (int j = 0; j < 4; ++j) {
                        int k = kb + j;
                        if (k < k_lo || k > k_hi) continue;
                        V[rowbase + k] = vals[rr * 64 + ((k & 63) ^ swz)];
                    }
                }
            }
        }
    }
}

// ---- split-K=4 GEMM, m97-exact single-buffer, L2-optimized XCD mapping.
// Each XCD owns ONE K-quarter (2 XCDs per quarter, bn split in halves);
// within an XCD, bm varies fastest so the 8 sharers of a V-panel are
// dispatch-adjacent. Streams/XCD: 8 x-panels (2 MB, L2-resident) + 16
// V-panel windows. grid (8,32,4)=1024 blocks = 4/CU.
__global__ __launch_bounds__(256, 4) void k_gemm_sk4(const unsigned short* __restrict__ A,
                                                     const unsigned short* __restrict__ Bv,
                                                     float* __restrict__ C,
                                                     float* __restrict__ part) {
    __shared__ unsigned short lA[128 * 64];   // 16 KB
    __shared__ unsigned short lB[128 * 64];   // 16 KB

    int flat = (blockIdx.z * 32 + blockIdx.y) * 8 + blockIdx.x;
    int xcd = flat & 7;          // HW round-robins consecutive blocks across XCDs
    int local = flat >> 3;       // 0..127, dispatch-time ordered within XCD
    int bz = xcd >> 1;           // one K-quarter per XCD pair
    int bn = (xcd & 1) * 16 + (local >> 3);
    int bm = local & 7;          // fastest -> V-panel sharers temporally aligned

    int tid = threadIdx.x;
    int lane = tid & 63;
    int wid = tid >> 6;
    int wm = wid >> 1, wn = wid & 1;

    int kbase = bz * (NN / 4);

    const unsigned short* aptr[4];
    const unsigned short* bptr[4];
#pragma unroll
    for (int c = 0; c < 4; ++c) {
        int u = c * 256 + tid;
        aptr[c] = A + ((size_t)(bm * 128 + (u >> 3)) * NN) + kbase + (u & 7) * 8;
        bptr[c] = Bv + ((size_t)(bn * 128 + (u >> 3)) * NN) + kbase + (u & 7) * 8;
    }

    f32x4 acc[4][4];
#pragma unroll
    for (int i = 0; i < 4; ++i)
#pragma unroll
        for (int j = 0; j < 4; ++j) acc[i][j] = (f32x4){0.f, 0.f, 0.f, 0.f};

    for (int kt = 0; kt < NN / 4 / 64; ++kt) {
#pragma unroll
        for (int c = 0; c < 4; ++c) {
            __builtin_amdgcn_global_load_lds(
                (const __attribute__((address_space(1))) uint32_t*)(aptr[c]),
                (__attribute__((address_space(3))) uint32_t*)(&lA[(c * 256 + tid) * 8]), 16, 0, 0);
            aptr[c] += 64;
            __builtin_amdgcn_global_load_lds(
                (const __attribute__((address_space(1))) uint32_t*)(bptr[c]),
                (__attribute__((address_space(3))) uint32_t*)(&lB[(c * 256 + tid) * 8]), 16, 0, 0);
            bptr[c] += 64;
        }
        __syncthreads();   // drains vmcnt -> LDS ready
#pragma unroll
        for (int kk = 0; kk < 2; ++kk) {
            bf16x8 af[4], bfr[4];
#pragma unroll
            for (int mf = 0; mf < 4; ++mf)
                af[mf] = *(const bf16x8*)&lA[(wm * 64 + mf * 16 + (lane & 15)) * 64 + kk * 32 + (lane >> 4) * 8];
#pragma unroll
            for (int nf = 0; nf < 4; ++nf)
                bfr[nf] = *(const bf16x8*)&lB[(wn * 64 + nf * 16 + (lane & 15)) * 64 + kk * 32 + (lane >> 4) * 8];
#pragma unroll
            for (int mf = 0; mf < 4; ++mf)
#pragma unroll
                for (int nf = 0; nf < 4; ++nf)
                    acc[mf][nf] = __builtin_amdgcn_mfma_f32_16x16x32_bf16(af[mf], bfr[nf], acc[mf][nf], 0, 0, 0);
        }
        __syncthreads();   // all waves done reading before next stage overwrites
    }

    float* dst = (bz == 0) ? C : (part + (size_t)(bz - 1) * BATCH * NN);
#pragma unroll
    for (int nf = 0; nf < 4; ++nf) {
        int col = bn * 128 + wn * 64 + nf * 16 + (lane & 15);
#pragma unroll
        for (int mf = 0; mf < 4; ++mf) {
            f32x4 v = acc[mf][nf];
            int row0 = bm * 128 + wm * 64 + mf * 16 + (lane >> 4) * 4;
#pragma unroll
            for (int r = 0; r < 4; ++r)
                dst[(size_t)(row0 + r) * NN + col] = v[r];
        }
    }
}

// ---- reduce4: C += part0+part1+part2 + bias ----
__global__ void k_reduce4(float4* __restrict__ C, const float4* __restrict__ p0,
                          const float4* __restrict__ p1, const float4* __restrict__ p2,
                          const float4* __restrict__ bias4) {
    int idx = blockIdx.x * 256 + threadIdx.x;   // BATCH*NN/4 exactly
    float4 c = C[idx], a = p0[idx], b = p1[idx], d = p2[idx];
    float4 e = bias4[idx & (NN / 4 - 1)];
    C[idx] = make_float4(c.x + a.x + b.x + d.x + e.x,
                         c.y + a.y + b.y + d.y + e.y,
                         c.z + a.z + b.z + d.z + e.z,
                         c.w + a.w + b.w + d.w + e.w);
}

// ---- split-K=2 GEMM (R7 path, used if ws too small for sk4) ----
__global__ __launch_bounds__(256) void k_gemm_sk(const unsigned short* __restrict__ A,
                                                 const unsigned short* __restrict__ Bv,
                                                 float* __restrict__ C,
                                                 float* __restrict__ part) {
    __shared__ unsigned short lA[2][128 * 64];
    __shared__ unsigned short lB[2][128 * 64];

    int flat = (blockIdx.z * 32 + blockIdx.y) * 8 + blockIdx.x;
    int swz = (flat & 7) * 64 + (flat >> 3);
    int bz = swz & 1;
    int bm = (swz >> 1) & 7;
    int bn = swz >> 4;

    int tid = threadIdx.x;
    int lane = tid & 63;
    int wid = tid >> 6;
    int wm = wid >> 1, wn = wid & 1;

    int kbase = bz * (NN / 2);

    const unsigned short* aptr[4];
    const unsigned short* bptr[4];
#pragma unroll
    for (int c = 0; c < 4; ++c) {
        int u = c * 256 + tid;
        aptr[c] = A + ((size_t)(bm * 128 + (u >> 3)) * NN) + kbase + (u & 7) * 8;
        bptr[c] = Bv + ((size_t)(bn * 128 + (u >> 3)) * NN) + kbase + (u & 7) * 8;
    }

    f32x4 acc[4][4];
#pragma unroll
    for (int i = 0; i < 4; ++i)
#pragma unroll
        for (int j = 0; j < 4; ++j) acc[i][j] = (f32x4){0.f, 0.f, 0.f, 0.f};

#define STAGE_SK(buf)                                                                \
    do {                                                                             \
        _Pragma("unroll") for (int c = 0; c < 4; ++c) {                              \
            __builtin_amdgcn_global_load_lds(                                        \
                (const __attribute__((address_space(1))) uint32_t*)(aptr[c]),        \
                (__attribute__((address_space(3))) uint32_t*)(&lA[buf][(c * 256 + tid) * 8]), \
                16, 0, 0);                                                           \
            aptr[c] += 64;                                                           \
            __builtin_amdgcn_global_load_lds(                                        \
                (const __attribute__((address_space(1))) uint32_t*)(bptr[c]),        \
                (__attribute__((address_space(3))) uint32_t*)(&lB[buf][(c * 256 + tid) * 8]), \
                16, 0, 0);                                                           \
            bptr[c] += 64;                                                           \
        }                                                                            \
    } while (0)

#define COMPUTE_SK(buf)                                                              \
    do {                                                                             \
        _Pragma("unroll") for (int kk = 0; kk < 2; ++kk) {                           \
            bf16x8 af[4], bfr[4];                                                    \
            _Pragma("unroll") for (int mf = 0; mf < 4; ++mf)                         \
                af[mf] = *(const bf16x8*)&lA[buf][(wm * 64 + mf * 16 + (lane & 15)) * 64 + kk * 32 + (lane >> 4) * 8]; \
            _Pragma("unroll") for (int nf = 0; nf < 4; ++nf)                         \
                bfr[nf] = *(const bf16x8*)&lB[buf][(wn * 64 + nf * 16 + (lane & 15)) * 64 + kk * 32 + (lane >> 4) * 8]; \
            _Pragma("unroll") for (int mf = 0; mf < 4; ++mf)                         \
                _Pragma("unroll") for (int nf = 0; nf < 4; ++nf)                     \
                    acc[mf][nf] = __builtin_amdgcn_mfma_f32_16x16x32_bf16(af[mf], bfr[nf], acc[mf][nf], 0, 0, 0); \
        }                                                                            \
    } while (0)

    STAGE_SK(0);
    __syncthreads();
    int cur = 0;
    for (int kt = 0; kt < NN / 2 / 64 - 1; ++kt) {
        STAGE_SK(cur ^ 1);
        COMPUTE_SK(cur);
        __syncthreads();
        cur ^= 1;
    }
    COMPUTE_SK(cur);
#undef STAGE_SK
#undef COMPUTE_SK

    float* dst = bz ? part : C;
#pragma unroll
    for (int nf = 0; nf < 4; ++nf) {
        int col = bn * 128 + wn * 64 + nf * 16 + (lane & 15);
#pragma unroll
        for (int mf = 0; mf < 4; ++mf) {
            f32x4 v = acc[mf][nf];
            int row0 = bm * 128 + wm * 64 + mf * 16 + (lane >> 4) * 4;
#pragma unroll
            for (int r = 0; r < 4; ++r)
                dst[(size_t)(row0 + r) * NN + col] = v[r];
        }
    }
}

// ---- reduce (split-K=2): out = C + part + bias ----
__global__ void k_reduce(float4* __restrict__ C, const float4* __restrict__ part,
                         const float4* __restrict__ bias4) {
    int idx = blockIdx.x * 256 + threadIdx.x;
    float4 p = C[idx];
    float4 q = part[idx];
    float4 b = bias4[idx & (NN / 4 - 1)];
    C[idx] = make_float4(p.x + q.x + b.x, p.y + q.y + b.y,
                         p.z + q.z + b.z, p.w + q.w + b.w);
}

// ---- fallback GEMM (no split): BM=64 x BN=128 ----
__global__ __launch_bounds__(256) void k_gemm(const unsigned short* __restrict__ A,
                                              const unsigned short* __restrict__ Bv,
                                              const float* __restrict__ bias,
                                              float* __restrict__ C) {
    __shared__ unsigned short lA[2][64 * 64];
    __shared__ unsigned short lB[2][128 * 64];

    int flat = blockIdx.y * 16 + blockIdx.x;
    int wg = (flat & 7) * 64 + (flat >> 3);
    int bm = wg & 15;
    int bn = wg >> 4;

    int tid = threadIdx.x;
    int lane = tid & 63;
    int wid = tid >> 6;
    int wm = wid >> 1, wn = wid & 1;

    const unsigned short* aptr[2];
    const unsigned short* bptr[4];
#pragma unroll
    for (int c = 0; c < 2; ++c) {
        int u = c * 256 + tid;
        aptr[c] = A + ((size_t)(bm * 64 + (u >> 3)) * NN) + (u & 7) * 8;
    }
#pragma unroll
    for (int c = 0; c < 4; ++c) {
        int u = c * 256 + tid;
        bptr[c] = Bv + ((size_t)(bn * 128 + (u >> 3)) * NN) + (u & 7) * 8;
    }

    f32x4 acc[2][4];
#pragma unroll
    for (int i = 0; i < 2; ++i)
#pragma unroll
        for (int j = 0; j < 4; ++j) acc[i][j] = (f32x4){0.f, 0.f, 0.f, 0.f};

#define STAGE(buf)                                                                   \
    do {                                                                             \
        _Pragma("unroll") for (int c = 0; c < 2; ++c) {                              \
            __builtin_amdgcn_global_load_lds(                                        \
                (const __attribute__((address_space(1))) uint32_t*)(aptr[c]),        \
                (__attribute__((address_space(3))) uint32_t*)(&lA[buf][(c * 256 + tid) * 8]), \
                16, 0, 0);                                                           \
            aptr[c] += 64;                                                           \
        }                                                                            \
        _Pragma("unroll") for (int c = 0; c < 4; ++c) {                              \
            __builtin_amdgcn_global_load_lds(                                        \
                (const __attribute__((address_space(1))) uint32_t*)(bptr[c]),        \
                (__attribute__((address_space(3))) uint32_t*)(&lB[buf][(c * 256 + tid) * 8]), \
                16, 0, 0);                                                           \
            bptr[c] += 64;                                                           \
        }                                                                            \
    } while (0)

#define COMPUTE(buf)                                                                 \
    do {                                                                             \
        _Pragma("unroll") for (int kk = 0; kk < 2; ++kk) {                           \
            bf16x8 af[2], bfr[4];                                                    \
            _Pragma("unroll") for (int mf = 0; mf < 2; ++mf)                         \
                af[mf] = *(const bf16x8*)&lA[buf][(wm * 32 + mf * 16 + (lane & 15)) * 64 + kk * 32 + (lane >> 4) * 8]; \
            _Pragma("unroll") for (int nf = 0; nf < 4; ++nf)                         \
                bfr[nf] = *(const bf16x8*)&lB[buf][(wn * 64 + nf * 16 + (lane & 15)) * 64 + kk * 32 + (lane >> 4) * 8]; \
            _Pragma("unroll") for (int mf = 0; mf < 2; ++mf)                         \
                _Pragma("unroll") for (int nf = 0; nf < 4; ++nf)                     \
                    acc[mf][nf] = __builtin_amdgcn_mfma_f32_16x16x32_bf16(af[mf], bfr[nf], acc[mf][nf], 0, 0, 0); \
        }                                                                            \
    } while (0)

    STAGE(0);
    __syncthreads();
    int cur = 0;
    for (int kt = 0; kt < NN / 64 - 1; ++kt) {
        STAGE(cur ^ 1);
        COMPUTE(cur);
        __syncthreads();
        cur ^= 1;
    }
    COMPUTE(cur);
#undef STAGE
#undef COMPUTE

#pragma unroll
    for (int nf = 0; nf < 4; ++nf) {
        int col = bn * 128 + wn * 64 + nf * 16 + (lane & 15);
        float bv = bias[col];
#pragma unroll
        for (int mf = 0; mf < 2; ++mf) {
            f32x4 v = acc[mf][nf];
            int row0 = bm * 64 + wm * 32 + mf * 16 + (lane >> 4) * 4;
#pragma unroll
            for (int r = 0; r < 4; ++r)
                C[(size_t)(row0 + r) * NN + col] = v[r] + bv;
        }
    }
}

extern "C" void kernel_launch(void* const* d_in, const int* in_sizes, int n_in,
                              void* d_out, int out_size, void* d_ws, size_t ws_size,
                              hipStream_t stream) {
    (void)in_sizes; (void)n_in; (void)out_size;
    const float* x  = (const float*)d_in[0];
    const float* sA = (const float*)d_in[1];
    const float* sB = (const float*)d_in[2];
    const float* G  = (const float*)d_in[3];
    const float* H  = (const float*)d_in[4];
    const float* bias = (const float*)d_in[5];
    float* out = (float*)d_out;

    char* ws = (char*)d_ws;
    unsigned short* V  = (unsigned short*)ws;               // 33,554,432 B
    float2* seg = (float2*)ws;                              // 4 MB, aliased on V (dead before pass3)
    unsigned short* xb = (unsigned short*)(ws + 33554432);  // 8,388,608 B
    float4* G4 = (float4*)(ws + 41943040);                  // 65,536 B
    float4* H4 = (float4*)(ws + 42008576);                  // 65,536 B
    float* carr = (float*)(ws + 42074112);                  // 2,097,152 B
    float* part = (float*)(ws + WS_PART_OFF);               // up to 3 x 16,777,216 B

    hipLaunchKernelGGL(k_prep, dim3(16), dim3(256), 0, stream, G, H, G4, H4);
    hipLaunchKernelGGL(k_convert, dim3((BATCH * NN / 4) / 256), dim3(256), 0, stream,
                       (const float4*)x, (ushort4*)xb);
    hipLaunchKernelGGL(k_pass1, dim3((NSEG * DPAD) / 256), dim3(256), 0, stream,
                       G4, H4, sA, sB, seg);
    hipLaunchKernelGGL(k_pass2, dim3(DPAD / 256), dim3(256), 0, stream, seg, carr);
    hipLaunchKernelGGL(k_pass3t, dim3(DPAD / DGRP, NN / TSEG), dim3(128), 0, stream,
                       G4, H4, sA, sB, carr, V);

    if (ws_size >= WS_SK4_NEED) {
        hipLaunchKernelGGL(k_gemm_sk4, dim3(8, 32, 4), dim3(256), 0, stream,
                           xb, V, out, part);
        hipLaunchKernelGGL(k_reduce4, dim3((BATCH * NN / 4) / 256), dim3(256), 0, stream,
                           (float4*)out, (const float4*)part,
                           (const float4*)(part + (size_t)BATCH * NN),
                           (const float4*)(part + 2ull * BATCH * NN),
                           (const float4*)bias);
    } else if (ws_size >= WS_SK2_NEED) {
        hipLaunchKernelGGL(k_gemm_sk, dim3(8, 32, 2), dim3(256), 0, stream,
                           xb, V, out, part);
        hipLaunchKernelGGL(k_reduce, dim3((BATCH * NN / 4) / 256), dim3(256), 0, stream,
                           (float4*)out, (const float4*)part, (const float4*)bias);
    } else {
        hipLaunchKernelGGL(k_gemm, dim3(BATCH / 64, NN / 128), dim3(256), 0, stream,
                           xb, V, bias, out);
    }
}

// Round 11
// 159.948 us; speedup vs baseline: 1.1727x; 1.1429x over previous
//
#include <hip/hip_runtime.h>
#include <hip/hip_bf16.h>
#include <stdint.h>

#define NN 4096
#define BATCH 1024
#define SEG 64          // carry granularity (steps)
#define NSEG 64
#define DPAD 8192
#define DGRP 128        // diagonals per pass3 block (sign-pure since NN-1 = 4095 ≡ 127 mod 128)
#define TSEG 64         // steps per pass3 block (== SEG)

#define WS_PART_OFF 44171264u
#define WS_SK2_NEED (WS_PART_OFF + (size_t)BATCH * NN * 4)
#define WS_SK4_NEED (WS_PART_OFF + 3ull * BATCH * NN * 4)

typedef __bf16 bf16x8 __attribute__((ext_vector_type(8)));
typedef float f32x4 __attribute__((ext_vector_type(4)));

__device__ __forceinline__ unsigned short f2bf(float f) {
    uint32_t u = __builtin_bit_cast(uint32_t, f);
    uint32_t r = (u + 0x7FFFu + ((u >> 16) & 1u)) >> 16;
    return (unsigned short)r;
}

// ---- transpose G,H (R x N, R=4) into float4-per-position arrays ----
__global__ void k_prep(const float* __restrict__ G, const float* __restrict__ H,
                       float4* __restrict__ G4, float4* __restrict__ H4) {
    int p = blockIdx.x * 256 + threadIdx.x;
    if (p < NN) {
        G4[p] = make_float4(G[p], G[NN + p], G[2 * NN + p], G[3 * NN + p]);
        H4[p] = make_float4(H[p], H[NN + p], H[2 * NN + p], H[3 * NN + p]);
    }
}

// ---- convert x fp32 -> bf16 ----
__global__ void k_convert(const float4* __restrict__ x4, ushort4* __restrict__ xb4) {
    int t = blockIdx.x * 256 + threadIdx.x;
    float4 a = x4[t];
    ushort4 o;
    o.x = f2bf(a.x); o.y = f2bf(a.y); o.z = f2bf(a.z); o.w = f2bf(a.w);
    xb4[t] = o;
}

// ---- pass 1: per-(diagonal, 64-step segment) affine map ----
__global__ void k_pass1(const float4* __restrict__ G4, const float4* __restrict__ H4,
                        const float* __restrict__ sA, const float* __restrict__ sB,
                        float2* __restrict__ seg) {
    int tid = blockIdx.x * 256 + threadIdx.x;
    int s = tid >> 13;
    int dd = tid & (DPAD - 1);
    int o = dd - (NN - 1);
    if (o > NN - 1) return;
    int ao = o < 0 ? -o : o;
    int L = NN - ao;
    int nseg = (L + SEG - 1) >> 6;
    if (s >= nseg) return;
    int t0 = s * SEG;
    int tend = t0 + SEG; if (tend > L) tend = L;
    float M = 0.f, Aacc = 1.f;
    for (int t = t0; t < tend; ++t) {
        int i = (o >= 0) ? (t + o) : t;
        int k = (o >= 0) ? t : (t - o);
        float4 g = G4[i], h = H4[k];
        float f = g.x * h.x + g.y * h.y + g.z * h.z + g.w * h.w;
        float c = (t == 0) ? 0.f : sA[i - 1] * sB[k - 1];
        M = fmaf(c, M, f);
        Aacc *= c;
    }
    seg[(size_t)s * DPAD + dd] = make_float2(Aacc, M);
}

// ---- pass 2: scan affine maps along each diagonal -> carry-in per segment ----
__global__ void k_pass2(const float2* __restrict__ seg, float* __restrict__ carr) {
    int dd = blockIdx.x * 256 + threadIdx.x;
    if (dd >= DPAD) return;
    int o = dd - (NN - 1);
    if (o > NN - 1) return;
    int ao = o < 0 ? -o : o;
    int L = NN - ao;
    int nseg = (L + SEG - 1) >> 6;
    float Min = 0.f;
    for (int s = 0; s < nseg; ++s) {
        carr[(size_t)s * DPAD + dd] = Min;
        float2 ab = seg[(size_t)s * DPAD + dd];
        Min = fmaf(ab.x, Min, ab.y);
    }
}

// ---- pass 3: sign-pure parallelogram tiles, 24.4 KB LDS (6 blocks/CU), 128 thr.
__global__ __launch_bounds__(128) void k_pass3t(
        const float4* __restrict__ G4, const float4* __restrict__ H4,
        const float* __restrict__ sA, const float* __restrict__ sB,
        const float* __restrict__ carr, unsigned short* __restrict__ V) {
    __shared__ unsigned short vals[191 * 64];   // 24,448 B (NEG uses first 16 KB)

    int dg = blockIdx.x;   // 0..63
    int sg = blockIdx.y;   // 0..63
    int dd0 = dg * DGRP;
    int t0 = sg * TSEG;
    int o0 = dd0 - (NN - 1);
    int o_hi = o0 + DGRP - 1;

    int minabs = (o0 >= 0) ? o0 : ((o_hi < 0) ? -o_hi : 0);
    if (t0 >= NN - minabs) return;

    int tid = threadIdx.x;   // 0..127, one diagonal each
    int dd = dd0 + tid;
    int o = dd - (NN - 1);
    float M = carr[(size_t)sg * DPAD + dd];

    if (o_hi <= 0) {
        // ---- NEG: i = t0+tl (uniform), k = t0+tl-o (per-lane, coalesced) ----
        int k0 = t0 - o;
#pragma unroll 4
        for (int tl = 0; tl < TSEG; ++tl) {
            int i = t0 + tl;
            int k = k0 + tl;
            int kc = k < NN ? k : NN - 1;
            float4 g = G4[i], h = H4[kc];
            float f = g.x * h.x + g.y * h.y + g.z * h.z + g.w * h.w;
            float c = 0.f;
            if (t0 + tl != 0) c = sA[i - 1] * sB[kc - 1];
            M = fmaf(c, M, f);
            vals[tl * 128 + ((k & 127) ^ ((tl & 15) << 2))] = f2bf(M);
        }
        __syncthreads();

        int row_sub = tid >> 5, csub = tid & 31;
        for (int rb = 0; rb < TSEG; rb += 4) {
            int tl = rb + row_sub;
            int i = t0 + tl;
            int swz = (tl & 15) << 2;
            int k_lo = i - o_hi;
            int k_hi = i - o0; if (k_hi > NN - 1) k_hi = NN - 1;
            size_t rowbase = (size_t)i * NN;
            int cb_first = k_lo >> 2, cb_last = k_hi >> 2;
            for (int cc = cb_first + csub; cc <= cb_last; cc += 32) {
                int kb = cc << 2;
                if (kb >= k_lo && kb + 3 <= k_hi) {
                    int c0 = (kb & 127) ^ swz;
                    *(ushort4*)&V[rowbase + kb] = *(const ushort4*)&vals[tl * 128 + c0];
                } else {
#pragma unroll
                    for (int j = 0; j < 4; ++j) {
                        int k = kb + j;
                        if (k < k_lo || k > k_hi) continue;
                        V[rowbase + k] = vals[tl * 128 + ((k & 127) ^ swz)];
                    }
                }
            }
        }
    } else {
        // ---- POS: k = t0+tl (uniform), i = t0+tl+o (per-lane, coalesced) ----
        int i0p = t0 + o;
#pragma unroll 4
        for (int tl = 0; tl < TSEG; ++tl) {
            int i = i0p + tl;
            int k = t0 + tl;
            int ic = i < NN ? i : NN - 1;
            float4 g = G4[ic], h = H4[k];
            float f = g.x * h.x + g.y * h.y + g.z * h.z + g.w * h.w;
            float c = 0.f;
            if (t0 + tl != 0) c = sA[ic - 1] * sB[k - 1];
            M = fmaf(c, M, f);
            int rr = tl + tid;
            vals[rr * 64 + ((k & 63) ^ ((rr & 15) << 2))] = f2bf(M);
        }
        __syncthreads();

        int i_lo = t0 + o0;
        int i_hi = t0 + TSEG - 1 + o_hi; if (i_hi > NN - 1) i_hi = NN - 1;
        int nrows = i_hi - i_lo + 1;
        int row_sub = tid >> 4, csub = tid & 15;
        for (int rb = 0; rb < nrows; rb += 8) {
            int rr = rb + row_sub;
            int i = i_lo + rr;
            if (i > i_hi) continue;
            int swz = (rr & 15) << 2;
            int k_lo = i - o_hi; if (k_lo < t0) k_lo = t0;
            int k_hi = i - o0;  if (k_hi > t0 + TSEG - 1) k_hi = t0 + TSEG - 1;
            size_t rowbase = (size_t)i * NN;
            int cb_first = k_lo >> 2, cb_last = k_hi >> 2;
            for (int cc = cb_first + csub; cc <= cb_last; cc += 16) {
                int kb = cc << 2;
                if (kb >= k_lo && kb + 3 <= k_hi) {
                    int c0 = (kb & 63) ^ swz;
                    *(ushort4*)&V[rowbase + kb] = *(const ushort4*)&vals[rr * 64 + c0];
                } else {
#pragma unroll
                    for (int j = 0; j < 4; ++j) {
                        int k = kb + j;
                        if (k < k_lo || k > k_hi) continue;
                        V[rowbase + k] = vals[rr * 64 + ((k & 63) ^ swz)];
                    }
                }
            }
        }
    }
}

// ---- split-K=4 GEMM: 256x256 tile, 8 waves (2M x 4N, wave = 128x64), BK=64,
// correct 2-phase double-buffer: __syncthreads() drains tile-u loads (compiler-
// enforced ordering), then STAGE(u+1 -> other slot) flies during COMPUTE(u).
// T2 both-sides swizzle (pre-swizzled global source + XOR'd ds_read).
// grid 256 (1/CU), 512 threads, 128 KB LDS.
__global__ __launch_bounds__(512, 2) void k_gemm_sk4(const unsigned short* __restrict__ A,
                                                     const unsigned short* __restrict__ Bv,
                                                     float* __restrict__ C,
                                                     float* __restrict__ part) {
    __shared__ unsigned short lA[2][256 * 64];   // 2 x 32 KB
    __shared__ unsigned short lB[2][256 * 64];   // 2 x 32 KB

    // XCD map: 2 XCDs per K-quarter; per XCD: 8 bn-panels x 4 bm (bm fastest)
    int flat = blockIdx.x;
    int xcd = flat & 7;
    int local = flat >> 3;            // 0..31
    int bz = xcd >> 1;
    int bn = (xcd & 1) * 8 + (local >> 2);
    int bm = local & 3;

    int tid = threadIdx.x;
    int lane = tid & 63;
    int wid = tid >> 6;               // 0..7
    int wm = wid >> 2;                // 0..1  (M half: rows wm*128..)
    int wn = wid & 3;                 // 0..3  (N quarter: rows wn*64.. of B)

    int kbase = bz * (NN / 4);

    // staging precompute: 4 chunks/thread per array (256 rows x 8 chunks)
    size_t srcOff[4];
    int ldsOff[4];
#pragma unroll
    for (int c = 0; c < 4; ++c) {
        int idx = c * 512 + tid;
        int row = idx >> 3;
        int cbyte = (idx & 7) << 4;
        // inverse-swizzled source so linear LDS write realizes the swizzle
        srcOff[c] = (size_t)row * NN + (size_t)((cbyte ^ ((row & 7) << 4)) >> 1);
        ldsOff[c] = idx * 8;          // linear LDS dest (elems)
    }
    const unsigned short* Abase = A + (size_t)(bm * 256) * NN + kbase;
    const unsigned short* Bbase = Bv + (size_t)(bn * 256) * NN + kbase;

    // read-side: swizzled ds_read offsets; row&7 == lane&7 for all frag rows
    int la15 = lane & 15, hi = lane >> 4;
    int swb = (lane & 7) << 4;
    int ce0 = ((hi * 16) ^ swb) >> 1;          // kk=0 (col bytes hi*16)
    int ce1 = ((64 + hi * 16) ^ swb) >> 1;     // kk=1 (col bytes 64+hi*16)

    f32x4 acc[8][4];
#pragma unroll
    for (int i = 0; i < 8; ++i)
#pragma unroll
        for (int j = 0; j < 4; ++j) acc[i][j] = (f32x4){0.f, 0.f, 0.f, 0.f};

#define STAGE_ALL(slot, kt)                                                          \
    do {                                                                             \
        _Pragma("unroll") for (int c = 0; c < 4; ++c) {                              \
            __builtin_amdgcn_global_load_lds(                                        \
                (const __attribute__((address_space(1))) uint32_t*)(Abase + (size_t)(kt) * 64 + srcOff[c]), \
                (__attribute__((address_space(3))) uint32_t*)(&lA[slot][0] + ldsOff[c]), 16, 0, 0); \
            __builtin_amdgcn_global_load_lds(                                        \
                (const __attribute__((address_space(1))) uint32_t*)(Bbase + (size_t)(kt) * 64 + srcOff[c]), \
                (__attribute__((address_space(3))) uint32_t*)(&lB[slot][0] + ldsOff[c]), 16, 0, 0); \
        }                                                                            \
    } while (0)

#define COMPUTE(slot)                                                                \
    do {                                                                             \
        _Pragma("unroll") for (int kk = 0; kk < 2; ++kk) {                           \
            int ce = kk ? ce1 : ce0;                                                 \
            bf16x8 af[8], bfr[4];                                                    \
            _Pragma("unroll") for (int mf = 0; mf < 8; ++mf)                         \
                af[mf] = *(const bf16x8*)&lA[slot][(wm * 128 + mf * 16 + la15) * 64 + ce]; \
            _Pragma("unroll") for (int nf = 0; nf < 4; ++nf)                         \
                bfr[nf] = *(const bf16x8*)&lB[slot][(wn * 64 + nf * 16 + la15) * 64 + ce]; \
            __builtin_amdgcn_s_setprio(1);                                           \
            _Pragma("unroll") for (int mf = 0; mf < 8; ++mf)                         \
            _Pragma("unroll") for (int nf = 0; nf < 4; ++nf)                         \
                acc[mf][nf] = __builtin_amdgcn_mfma_f32_16x16x32_bf16(af[mf], bfr[nf], acc[mf][nf], 0, 0, 0); \
            __builtin_amdgcn_s_setprio(0);                                           \
        }                                                                            \
    } while (0)

    STAGE_ALL(0, 0);
    for (int u = 0; u < 16; ++u) {
        int s = u & 1;
        __syncthreads();              // drains tile-u loads; orders vs slot-s rewrite
        if (u < 15) STAGE_ALL(s ^ 1, u + 1);   // in flight during COMPUTE
        COMPUTE(s);
    }
#undef STAGE_ALL
#undef COMPUTE

    float* dst = (bz == 0) ? C : (part + (size_t)(bz - 1) * BATCH * NN);
#pragma unroll
    for (int mf = 0; mf < 8; ++mf) {
#pragma unroll
        for (int nf = 0; nf < 4; ++nf) {
            f32x4 v = acc[mf][nf];
            int col = bn * 256 + wn * 64 + nf * 16 + la15;
            int r0 = bm * 256 + wm * 128 + mf * 16 + hi * 4;
#pragma unroll
            for (int r = 0; r < 4; ++r)
                dst[(size_t)(r0 + r) * NN + col] = v[r];
        }
    }
}

// ---- reduce4: C += part0+part1+part2 + bias ----
__global__ void k_reduce4(float4* __restrict__ C, const float4* __restrict__ p0,
                          const float4* __restrict__ p1, const float4* __restrict__ p2,
                          const float4* __restrict__ bias4) {
    int idx = blockIdx.x * 256 + threadIdx.x;   // BATCH*NN/4 exactly
    float4 c = C[idx], a = p0[idx], b = p1[idx], d = p2[idx];
    float4 e = bias4[idx & (NN / 4 - 1)];
    C[idx] = make_float4(c.x + a.x + b.x + d.x + e.x,
                         c.y + a.y + b.y + d.y + e.y,
                         c.z + a.z + b.z + d.z + e.z,
                         c.w + a.w + b.w + d.w + e.w);
}

// ---- split-K=2 GEMM (fallback if ws too small for sk4) ----
__global__ __launch_bounds__(256) void k_gemm_sk(const unsigned short* __restrict__ A,
                                                 const unsigned short* __restrict__ Bv,
                                                 float* __restrict__ C,
                                                 float* __restrict__ part) {
    __shared__ unsigned short lA[2][128 * 64];
    __shared__ unsigned short lB[2][128 * 64];

    int flat = (blockIdx.z * 32 + blockIdx.y) * 8 + blockIdx.x;
    int swz = (flat & 7) * 64 + (flat >> 3);
    int bz = swz & 1;
    int bm = (swz >> 1) & 7;
    int bn = swz >> 4;

    int tid = threadIdx.x;
    int lane = tid & 63;
    int wid = tid >> 6;
    int wm = wid >> 1, wn = wid & 1;

    int kbase = bz * (NN / 2);

    const unsigned short* aptr[4];
    const unsigned short* bptr[4];
#pragma unroll
    for (int c = 0; c < 4; ++c) {
        int u = c * 256 + tid;
        aptr[c] = A + ((size_t)(bm * 128 + (u >> 3)) * NN) + kbase + (u & 7) * 8;
        bptr[c] = Bv + ((size_t)(bn * 128 + (u >> 3)) * NN) + kbase + (u & 7) * 8;
    }

    f32x4 acc[4][4];
#pragma unroll
    for (int i = 0; i < 4; ++i)
#pragma unroll
        for (int j = 0; j < 4; ++j) acc[i][j] = (f32x4){0.f, 0.f, 0.f, 0.f};

#define STAGE_SK(buf)                                                                \
    do {                                                                             \
        _Pragma("unroll") for (int c = 0; c < 4; ++c) {                              \
            __builtin_amdgcn_global_load_lds(                                        \
                (const __attribute__((address_space(1))) uint32_t*)(aptr[c]),        \
                (__attribute__((address_space(3))) uint32_t*)(&lA[buf][(c * 256 + tid) * 8]), \
                16, 0, 0);                                                           \
            aptr[c] += 64;                                                           \
            __builtin_amdgcn_global_load_lds(                                        \
                (const __attribute__((address_space(1))) uint32_t*)(bptr[c]),        \
                (__attribute__((address_space(3))) uint32_t*)(&lB[buf][(c * 256 + tid) * 8]), \
                16, 0, 0);                                                           \
            bptr[c] += 64;                                                           \
        }                                                                            \
    } while (0)

#define COMPUTE_SK(buf)                                                              \
    do {                                                                             \
        _Pragma("unroll") for (int kk = 0; kk < 2; ++kk) {                           \
            bf16x8 af[4], bfr[4];                                                    \
            _Pragma("unroll") for (int mf = 0; mf < 4; ++mf)                         \
                af[mf] = *(const bf16x8*)&lA[buf][(wm * 64 + mf * 16 + (lane & 15)) * 64 + kk * 32 + (lane >> 4) * 8]; \
            _Pragma("unroll") for (int nf = 0; nf < 4; ++nf)                         \
                bfr[nf] = *(const bf16x8*)&lB[buf][(wn * 64 + nf * 16 + (lane & 15)) * 64 + kk * 32 + (lane >> 4) * 8]; \
            _Pragma("unroll") for (int mf = 0; mf < 4; ++mf)                         \
                _Pragma("unroll") for (int nf = 0; nf < 4; ++nf)                     \
                    acc[mf][nf] = __builtin_amdgcn_mfma_f32_16x16x32_bf16(af[mf], bfr[nf], acc[mf][nf], 0, 0, 0); \
        }                                                                            \
    } while (0)

    STAGE_SK(0);
    __syncthreads();
    int cur = 0;
    for (int kt = 0; kt < NN / 2 / 64 - 1; ++kt) {
        STAGE_SK(cur ^ 1);
        COMPUTE_SK(cur);
        __syncthreads();
        cur ^= 1;
    }
    COMPUTE_SK(cur);
#undef STAGE_SK
#undef COMPUTE_SK

    float* dst = bz ? part : C;
#pragma unroll
    for (int nf = 0; nf < 4; ++nf) {
        int col = bn * 128 + wn * 64 + nf * 16 + (lane & 15);
#pragma unroll
        for (int mf = 0; mf < 4; ++mf) {
            f32x4 v = acc[mf][nf];
            int row0 = bm * 128 + wm * 64 + mf * 16 + (lane >> 4) * 4;
#pragma unroll
            for (int r = 0; r < 4; ++r)
                dst[(size_t)(row0 + r) * NN + col] = v[r];
        }
    }
}

// ---- reduce (split-K=2): out = C + part + bias ----
__global__ void k_reduce(float4* __restrict__ C, const float4* __restrict__ part,
                         const float4* __restrict__ bias4) {
    int idx = blockIdx.x * 256 + threadIdx.x;
    float4 p = C[idx];
    float4 q = part[idx];
    float4 b = bias4[idx & (NN / 4 - 1)];
    C[idx] = make_float4(p.x + q.x + b.x, p.y + q.y + b.y,
                         p.z + q.z + b.z, p.w + q.w + b.w);
}

extern "C" void kernel_launch(void* const* d_in, const int* in_sizes, int n_in,
                              void* d_out, int out_size, void* d_ws, size_t ws_size,
                              hipStream_t stream) {
    (void)in_sizes; (void)n_in; (void)out_size;
    const float* x  = (const float*)d_in[0];
    const float* sA = (const float*)d_in[1];
    const float* sB = (const float*)d_in[2];
    const float* G  = (const float*)d_in[3];
    const float* H  = (const float*)d_in[4];
    const float* bias = (const float*)d_in[5];
    float* out = (float*)d_out;

    char* ws = (char*)d_ws;
    unsigned short* V  = (unsigned short*)ws;               // 33,554,432 B
    float2* seg = (float2*)ws;                              // 4 MB, aliased on V (dead before pass3)
    unsigned short* xb = (unsigned short*)(ws + 33554432);  // 8,388,608 B
    float4* G4 = (float4*)(ws + 41943040);                  // 65,536 B
    float4* H4 = (float4*)(ws + 42008576);                  // 65,536 B
    float* carr = (float*)(ws + 42074112);                  // 2,097,152 B
    float* part = (float*)(ws + WS_PART_OFF);               // up to 3 x 16,777,216 B

    hipLaunchKernelGGL(k_prep, dim3(16), dim3(256), 0, stream, G, H, G4, H4);
    hipLaunchKernelGGL(k_convert, dim3((BATCH * NN / 4) / 256), dim3(256), 0, stream,
                       (const float4*)x, (ushort4*)xb);
    hipLaunchKernelGGL(k_pass1, dim3((NSEG * DPAD) / 256), dim3(256), 0, stream,
                       G4, H4, sA, sB, seg);
    hipLaunchKernelGGL(k_pass2, dim3(DPAD / 256), dim3(256), 0, stream, seg, carr);
    hipLaunchKernelGGL(k_pass3t, dim3(DPAD / DGRP, NN / TSEG), dim3(128), 0, stream,
                       G4, H4, sA, sB, carr, V);

    if (ws_size >= WS_SK4_NEED) {
        hipLaunchKernelGGL(k_gemm_sk4, dim3(256), dim3(512), 0, stream,
                           xb, V, out, part);
        hipLaunchKernelGGL(k_reduce4, dim3((BATCH * NN / 4) / 256), dim3(256), 0, stream,
                           (float4*)out, (const float4*)part,
                           (const float4*)(part + (size_t)BATCH * NN),
                           (const float4*)(part + 2ull * BATCH * NN),
                           (const float4*)bias);
    } else {
        hipLaunchKernelGGL(k_gemm_sk, dim3(8, 32, 2), dim3(256), 0, stream,
                           xb, V, out, part);
        hipLaunchKernelGGL(k_reduce, dim3((BATCH * NN / 4) / 256), dim3(256), 0, stream,
                           (float4*)out, (const float4*)part, (const float4*)bias);
    }
}